// Round 3
// baseline (794.925 us; speedup 1.0000x reference)
//
#include <hip/hip_runtime.h>

#define T 2048
#define D 1024
#define F 4096
#define E 8
#define NS 8
#define FS 512
#define SHB 5120      // shared-expert H base row (routed padded capacity)
#define NROWS 7168    // SHB + T
#define MT_MAX 56     // NROWS/128

typedef short short8 __attribute__((ext_vector_type(8)));
typedef float floatx16 __attribute__((ext_vector_type(16)));

__device__ __forceinline__ unsigned short f2bf(float f) {
  unsigned int u = __float_as_uint(f);
  u += 0x7FFF + ((u >> 16) & 1);   // RNE
  return (unsigned short)(u >> 16);
}

__device__ __forceinline__ void glds16(const void* g, void* l) {
  __builtin_amdgcn_global_load_lds(
      (const __attribute__((address_space(1))) void*)g,
      (__attribute__((address_space(3))) void*)l, 16, 0, 0);
}

// ---------------- gate: logits, softmax, top-2, x -> bf16 ----------------
__global__ void gate_kernel(const float* __restrict__ x, const float* __restrict__ gW,
                            unsigned short* __restrict__ xb, int* __restrict__ cnt,
                            int* __restrict__ list_tok, float* __restrict__ list_gate) {
  int t = blockIdx.x, tid = threadIdx.x;
  const float* xr = x + (size_t)t * D;
  float acc[E];
#pragma unroll
  for (int e = 0; e < E; ++e) acc[e] = 0.f;
  for (int d = tid; d < D; d += 256) {
    float xv = xr[d];
    xb[(size_t)t * D + d] = f2bf(xv);
#pragma unroll
    for (int e = 0; e < E; ++e) acc[e] += xv * gW[e * D + d];
  }
#pragma unroll
  for (int o = 32; o > 0; o >>= 1)
#pragma unroll
    for (int e = 0; e < E; ++e) acc[e] += __shfl_down(acc[e], o, 64);
  __shared__ float wred[4][E];
  int lane = tid & 63, wv = tid >> 6;
  if (lane == 0)
#pragma unroll
    for (int e = 0; e < E; ++e) wred[wv][e] = acc[e];
  __syncthreads();
  if (tid == 0) {
    float l[E];
#pragma unroll
    for (int e = 0; e < E; ++e) l[e] = wred[0][e] + wred[1][e] + wred[2][e] + wred[3][e];
    int i1 = 0; float m1 = l[0];
    for (int e = 1; e < E; ++e) if (l[e] > m1) { m1 = l[e]; i1 = e; }
    int i2 = -1; float m2 = -3.4e38f;
    for (int e = 0; e < E; ++e) if (e != i1 && l[e] > m2) { m2 = l[e]; i2 = e; }
    float s = 0.f, p[E];
#pragma unroll
    for (int e = 0; e < E; ++e) { p[e] = __expf(l[e] - m1); s += p[e]; }
    float inv = 1.f / s;
    int p1 = atomicAdd(&cnt[i1], 1);
    list_tok[i1 * T + p1] = t; list_gate[i1 * T + p1] = p[i1] * inv;
    int p2 = atomicAdd(&cnt[i2], 1);
    list_tok[i2 * T + p2] = t; list_gate[i2 * T + p2] = p[i2] * inv;
  }
}

// ---------------- offsets (1 thread): 128-aligned segment starts ----------------
__global__ void offsets_kernel(const int* __restrict__ cnt, int* __restrict__ off,
                               int* __restrict__ mt_expert) {
  if (threadIdx.x == 0 && blockIdx.x == 0) {
    int o = 0;
    for (int e = 0; e < E; ++e) { off[e] = o; o += (cnt[e] + 127) & ~127; }
    off[E] = o;
    for (int i = 0; i < MT_MAX; ++i) mt_expert[i] = -1;
    for (int e = 0; e < E; ++e) {
      int t0 = off[e] >> 7, nt = (cnt[e] + 127) >> 7;
      for (int i = 0; i < nt; ++i) mt_expert[t0 + i] = e;
    }
    for (int i = SHB >> 7; i < MT_MAX; ++i) mt_expert[i] = E;
  }
}

// ---------------- scatter: row maps + per-row scales ----------------
__global__ void scatter_kernel(const int* __restrict__ cnt, const int* __restrict__ off,
                               const int* __restrict__ list_tok, const float* __restrict__ list_gate,
                               int* __restrict__ tok_of_row, float* __restrict__ row_scale) {
  int idx = blockIdx.x * 256 + threadIdx.x;  // E*T
  int e = idx >> 11, i = idx & (T - 1);
  if (e < E && i < cnt[e]) {
    int row = off[e] + i;
    tok_of_row[row] = list_tok[e * T + i];
    row_scale[row] = 0.5f * list_gate[e * T + i];
  }
}

// ------- merged transpose+cast: fp32 [R,C] -> bf16 tiled [C/128][R/32][128][32] -------
// 64x64 tiles, one launch for all 6 weight tensors.
struct TPtrs {
  const float* src[6];
  unsigned short* dst[6];
};
__global__ void transpose_all(TPtrs p) {
  int b = blockIdx.x;
  const float* src; unsigned short* dst;
  int R, C, csh, sl, t;
  if (b < 8192)       { src = p.src[0]; dst = p.dst[0]; R = 1024; C = 4096; csh = 6; sl = b >> 10; t = b & 1023; }
  else if (b < 16384) { b -= 8192;  src = p.src[1]; dst = p.dst[1]; R = 1024; C = 4096; csh = 6; sl = b >> 10; t = b & 1023; }
  else if (b < 24576) { b -= 16384; src = p.src[2]; dst = p.dst[2]; R = 4096; C = 1024; csh = 4; sl = b >> 10; t = b & 1023; }
  else if (b < 25600) { b -= 24576; src = p.src[3]; dst = p.dst[3]; R = 1024; C = 512;  csh = 3; sl = b >> 7;  t = b & 127; }
  else if (b < 26624) { b -= 25600; src = p.src[4]; dst = p.dst[4]; R = 1024; C = 512;  csh = 3; sl = b >> 7;  t = b & 127; }
  else                { b -= 26624; src = p.src[5]; dst = p.dst[5]; R = 4096; C = 1024; csh = 4; sl = 0;       t = b; }
  src += (size_t)sl * R * C;
  dst += (size_t)sl * R * C;
  int rt = t >> csh, ct = t & ((1 << csh) - 1);
  int r0 = rt * 64, c0 = ct * 64;
  __shared__ float tile[64][65];
  int tid = threadIdx.x;
#pragma unroll
  for (int pp = 0; pp < 4; ++pp) {
    int idx = pp * 256 + tid;
    int rl = idx >> 4, cl = (idx & 15) * 4;
    float4 v = *(const float4*)(src + (size_t)(r0 + rl) * C + c0 + cl);
    tile[rl][cl] = v.x; tile[rl][cl + 1] = v.y;
    tile[rl][cl + 2] = v.z; tile[rl][cl + 3] = v.w;
  }
  __syncthreads();
  int Rt = R >> 5;
#pragma unroll
  for (int pp = 0; pp < 2; ++pp) {
    int idx = pp * 256 + tid;
    int cl = idx >> 3, r8 = (idx & 7) * 8;
    int c = c0 + cl, r = r0 + r8;
    short8 v;
#pragma unroll
    for (int i = 0; i < 8; ++i) v[i] = (short)f2bf(tile[r8 + i][cl]);
    size_t o = ((size_t)(c >> 7) * Rt + (r >> 5)) * 4096 + (size_t)(c & 127) * 32 + (r & 31);
    *(short8*)(dst + o) = v;
  }
}

// ---------------- up GEMM: H = silu(A@W1) * (A@W3), 32x32x16 MFMA ----------------
// LDS XOR-swizzle: 16B slot j of row r holds global slot j ^ ((r>>1)&3)
__global__ __launch_bounds__(256, 2) void up_gemm(
    const unsigned short* __restrict__ xb, const unsigned short* __restrict__ W1T,
    const unsigned short* __restrict__ W3T, const unsigned short* __restrict__ W1sT,
    const unsigned short* __restrict__ W3sT, const int* __restrict__ mt_expert,
    const int* __restrict__ tok_of_row, unsigned short* __restrict__ Hb) {
  int mt = blockIdx.x, ntile = blockIdx.y;
  int e = mt_expert[mt];
  if (e < 0) return;
  const unsigned short *B1, *B3;
  if (e < E) {
    B1 = W1T + (size_t)e * F * D;
    B3 = W3T + (size_t)e * F * D;
  } else {
    B1 = W1sT; B3 = W3sT;
  }
  __shared__ unsigned short Al[128 * 32];
  __shared__ unsigned short B1l[128 * 32];
  __shared__ unsigned short B3l[128 * 32];
  int tid = threadIdx.x;
  int lane = tid & 63, wv = tid >> 6, wm = wv >> 1, wn = wv & 1;
  int l31 = lane & 31, lh = lane >> 5;
  int key = (l31 >> 1) & 3;
  int slot0 = (lh ^ key) * 8, slot1 = ((2 + lh) ^ key) * 8;     // shorts
  int swzb = (tid & ~3) * 16 + (((tid & 3) ^ ((tid >> 3) & 3)) * 16);  // staging src byte off

  int ar = tid >> 1;                 // staged row 0..127 (2 threads/row)
  int hrow_s = mt * 128 + ar;
  int srow = (e < E) ? tok_of_row[hrow_s] : (hrow_s - SHB);
  int ja = (tid & 1) * 2;
  int sa = (tid >> 2) & 3;
  const uint4* aptr = (const uint4*)(xb + (size_t)srow * D) + ja;
  uint4* alds0 = (uint4*)Al + ar * 4 + (ja ^ sa);
  uint4* alds1 = (uint4*)Al + ar * 4 + ((ja + 1) ^ sa);

  const unsigned short* b1t = B1 + (size_t)ntile * (D / 32) * 4096;
  const unsigned short* b3t = B3 + (size_t)ntile * (D / 32) * 4096;

  floatx16 accg[2][2], accu[2][2];
#pragma unroll
  for (int i = 0; i < 2; ++i)
#pragma unroll
    for (int j = 0; j < 2; ++j) {
      accg[i][j] = (floatx16)(0.f);
      accu[i][j] = (floatx16)(0.f);
    }
  int lw = wv * 1024;
  for (int kt = 0; kt < D / 32; ++kt) {
    uint4 av0 = aptr[0];
    uint4 av1 = aptr[1];
    const char* b1s = (const char*)(b1t + (size_t)kt * 4096);
    const char* b3s = (const char*)(b3t + (size_t)kt * 4096);
    glds16(b1s + swzb, (char*)B1l + lw);
    glds16(b1s + 4096 + swzb, (char*)B1l + 4096 + lw);
    glds16(b3s + swzb, (char*)B3l + lw);
    glds16(b3s + 4096 + swzb, (char*)B3l + 4096 + lw);
    alds0[0] = av0; alds1[0] = av1;
    __syncthreads();
#pragma unroll
    for (int s = 0; s < 2; ++s) {
      int so = s ? slot1 : slot0;
      short8 af[2], b1f[2], b3f[2];
#pragma unroll
      for (int mi = 0; mi < 2; ++mi)
        af[mi] = *(const short8*)(Al + (wm * 64 + mi * 32 + l31) * 32 + so);
#pragma unroll
      for (int ni = 0; ni < 2; ++ni) {
        int rb = (wn * 64 + ni * 32 + l31) * 32 + so;
        b1f[ni] = *(const short8*)(B1l + rb);
        b3f[ni] = *(const short8*)(B3l + rb);
      }
#pragma unroll
      for (int mi = 0; mi < 2; ++mi)
#pragma unroll
        for (int ni = 0; ni < 2; ++ni) {
          accg[mi][ni] = __builtin_amdgcn_mfma_f32_32x32x16_bf16(af[mi], b1f[ni], accg[mi][ni], 0, 0, 0);
          accu[mi][ni] = __builtin_amdgcn_mfma_f32_32x32x16_bf16(af[mi], b3f[ni], accu[mi][ni], 0, 0, 0);
        }
    }
    aptr += 4;
    __syncthreads();
  }
  // epilogue: silu(g)*u -> bf16, H in tiled layout
#pragma unroll
  for (int mi = 0; mi < 2; ++mi)
#pragma unroll
    for (int ni = 0; ni < 2; ++ni)
#pragma unroll
      for (int r = 0; r < 16; ++r) {
        int rowin = (r & 3) + 8 * (r >> 2) + 4 * lh;
        int hrow = mt * 128 + wm * 64 + mi * 32 + rowin;
        int col = ntile * 128 + wn * 64 + ni * 32 + l31;
        float g = accg[mi][ni][r], u = accu[mi][ni][r];
        float h = g * u / (1.0f + __expf(-g));
        size_t o = ((size_t)mt * 128 + (col >> 5)) * 4096 + (size_t)(hrow & 127) * 32 + (col & 31);
        Hb[o] = f2bf(h);
      }
}

// ---------------- down GEMM: out += (H @ W2) * row_scale, split-K x2, atomic ----------------
__global__ __launch_bounds__(256, 2) void down_gemm(
    const unsigned short* __restrict__ Hb, const unsigned short* __restrict__ W2T,
    const unsigned short* __restrict__ W2sT, const int* __restrict__ mt_expert,
    const int* __restrict__ tok_of_row, const float* __restrict__ row_scale,
    float* __restrict__ out) {
  int mt = blockIdx.x, ntile = blockIdx.y, kz = blockIdx.z;
  int e = mt_expert[mt];
  if (e < 0) return;
  const unsigned short* Bt = ((e < E) ? (W2T + (size_t)e * D * F) : W2sT)
                             + (size_t)ntile * (F / 32) * 4096;
  const unsigned short* At = Hb + (size_t)mt * (F / 32) * 4096;
  __shared__ unsigned short Al[128 * 32];
  __shared__ unsigned short Bl[128 * 32];
  int tid = threadIdx.x;
  int lane = tid & 63, wv = tid >> 6, wm = wv >> 1, wn = wv & 1;
  int l31 = lane & 31, lh = lane >> 5;
  int key = (l31 >> 1) & 3;
  int slot0 = (lh ^ key) * 8, slot1 = ((2 + lh) ^ key) * 8;
  int swzb = (tid & ~3) * 16 + (((tid & 3) ^ ((tid >> 3) & 3)) * 16);
  floatx16 acc[2][2];
#pragma unroll
  for (int i = 0; i < 2; ++i)
#pragma unroll
    for (int j = 0; j < 2; ++j) acc[i][j] = (floatx16)(0.f);
  int lw = wv * 1024;
  for (int kt = kz * 64; kt < kz * 64 + 64; ++kt) {
    const char* as = (const char*)(At + (size_t)kt * 4096);
    const char* bs = (const char*)(Bt + (size_t)kt * 4096);
    glds16(as + swzb, (char*)Al + lw);
    glds16(as + 4096 + swzb, (char*)Al + 4096 + lw);
    glds16(bs + swzb, (char*)Bl + lw);
    glds16(bs + 4096 + swzb, (char*)Bl + 4096 + lw);
    __syncthreads();
#pragma unroll
    for (int s = 0; s < 2; ++s) {
      int so = s ? slot1 : slot0;
      short8 af[2], bf[2];
#pragma unroll
      for (int mi = 0; mi < 2; ++mi)
        af[mi] = *(const short8*)(Al + (wm * 64 + mi * 32 + l31) * 32 + so);
#pragma unroll
      for (int ni = 0; ni < 2; ++ni)
        bf[ni] = *(const short8*)(Bl + (wn * 64 + ni * 32 + l31) * 32 + so);
#pragma unroll
      for (int mi = 0; mi < 2; ++mi)
#pragma unroll
        for (int ni = 0; ni < 2; ++ni)
          acc[mi][ni] = __builtin_amdgcn_mfma_f32_32x32x16_bf16(af[mi], bf[ni], acc[mi][ni], 0, 0, 0);
    }
    __syncthreads();
  }
#pragma unroll
  for (int mi = 0; mi < 2; ++mi)
#pragma unroll
    for (int r = 0; r < 16; ++r) {
      int rowin = (r & 3) + 8 * (r >> 2) + 4 * lh;
      int grow = mt * 128 + wm * 64 + mi * 32 + rowin;
      int tok; float scale;
      if (grow < SHB) { tok = tok_of_row[grow]; scale = row_scale[grow]; }
      else            { tok = grow - SHB;       scale = 0.0625f; }
      float* orow = out + (size_t)tok * D;
#pragma unroll
      for (int ni = 0; ni < 2; ++ni) {
        int col = ntile * 128 + wn * 64 + ni * 32 + l31;
        unsafeAtomicAdd(orow + col, acc[mi][ni][r] * scale);
      }
    }
}

extern "C" void kernel_launch(void* const* d_in, const int* in_sizes, int n_in,
                              void* d_out, int out_size, void* d_ws, size_t ws_size,
                              hipStream_t stream) {
  (void)in_sizes; (void)n_in; (void)out_size; (void)ws_size;
  const float* x   = (const float*)d_in[0];
  const float* gW  = (const float*)d_in[1];
  float* out = (float*)d_out;

  char* w = (char*)d_ws;
  auto alloc = [&](size_t bytes) {
    char* p = w; w += (bytes + 255) & ~(size_t)255; return p;
  };
  unsigned short* xb   = (unsigned short*)alloc((size_t)T * D * 2);
  unsigned short* W1T  = (unsigned short*)alloc((size_t)E * F * D * 2);
  unsigned short* W3T  = (unsigned short*)alloc((size_t)E * F * D * 2);
  unsigned short* W2T  = (unsigned short*)alloc((size_t)E * D * F * 2);
  unsigned short* W1sT = (unsigned short*)alloc((size_t)F * D * 2);
  unsigned short* W3sT = (unsigned short*)alloc((size_t)F * D * 2);
  unsigned short* W2sT = (unsigned short*)alloc((size_t)D * F * 2);
  unsigned short* Hb   = (unsigned short*)alloc((size_t)NROWS * F * 2);
  float* list_gate = (float*)alloc((size_t)E * T * 4);
  int* list_tok    = (int*)alloc((size_t)E * T * 4);
  int* offv        = (int*)alloc(16 * 4);
  int* mt_expert   = (int*)alloc(64 * 4);
  int* ctrl        = (int*)alloc((size_t)(8 + SHB + SHB) * 4);
  int* cnt = ctrl;
  int* tok_of_row  = ctrl + 8;
  float* row_scale = (float*)(ctrl + 8 + SHB);

  hipMemsetAsync(ctrl, 0, (size_t)(8 + SHB + SHB) * 4, stream);
  hipMemsetAsync(out, 0, (size_t)T * D * 4, stream);
  gate_kernel<<<T, 256, 0, stream>>>(x, gW, xb, cnt, list_tok, list_gate);
  offsets_kernel<<<1, 64, 0, stream>>>(cnt, offv, mt_expert);
  scatter_kernel<<<(E * T) / 256, 256, 0, stream>>>(cnt, offv, list_tok, list_gate,
                                                    tok_of_row, row_scale);
  TPtrs tp;
  tp.src[0] = (const float*)d_in[2]; tp.dst[0] = W1T;
  tp.src[1] = (const float*)d_in[3]; tp.dst[1] = W3T;
  tp.src[2] = (const float*)d_in[4]; tp.dst[2] = W2T;
  tp.src[3] = (const float*)d_in[5]; tp.dst[3] = W1sT;
  tp.src[4] = (const float*)d_in[6]; tp.dst[4] = W3sT;
  tp.src[5] = (const float*)d_in[7]; tp.dst[5] = W2sT;
  transpose_all<<<27648, 256, 0, stream>>>(tp);
  up_gemm<<<dim3(MT_MAX, F / 128), 256, 0, stream>>>(xb, W1T, W3T, W1sT, W3sT,
                                                     mt_expert, tok_of_row, Hb);
  down_gemm<<<dim3(MT_MAX, D / 128, 2), 256, 0, stream>>>(Hb, W2T, W2sT, mt_expert,
                                                          tok_of_row, row_scale, out);
}